// Round 1
// baseline (3605.624 us; speedup 1.0000x reference)
//
#include <hip/hip_runtime.h>
#include <math.h>

// Problem constants
#define LL 4096
#define BATCH 32
#define NIC 128
#define NFC 128

__device__ __forceinline__ unsigned short f2bf(float f) {
  unsigned u = __builtin_bit_cast(unsigned, f);
  u += 0x7fffu + ((u >> 16) & 1u);  // round-to-nearest-even
  return (unsigned short)(u >> 16);
}
__device__ __forceinline__ float bf2f(unsigned short h) {
  unsigned u = ((unsigned)h) << 16;
  return __builtin_bit_cast(float, u);
}

// ---------------------------------------------------------------------------
// Weight transpose: src [O=128][I=128][K] -> dst [(ci*K + k)*128 + o]
// so the conv inner loop reads 8 consecutive o's per (ci,k) as 2x float4.
// ---------------------------------------------------------------------------
__global__ void wtrans(const float* __restrict__ src, float* __restrict__ dst,
                       int K, int n) {
  int f = blockIdx.x * 256 + threadIdx.x;
  if (f >= n) return;
  int o   = f / (128 * K);
  int rem = f - o * 128 * K;
  int ci  = rem / K;
  int k   = rem - ci * K;
  dst[(ci * K + k) * 128 + o] = src[f];
}

// ---------------------------------------------------------------------------
// Conv branch: per block (b, l-tile of 128), all 128 out channels.
// Thread tile 8o x 8l (16x16 thread grid). x staged in LDS in 2 ci-chunks.
// Writes F (bf16) and accumulates GAP partial sums (fp32 atomics).
// MP=true: maxpool3(same) then 1x1 conv; halo padded with -inf.
// ---------------------------------------------------------------------------
template <int K, bool MP>
__launch_bounds__(256)
__global__ void conv_branch(const float* __restrict__ x,
                            const float* __restrict__ wt,
                            unsigned short* __restrict__ Fout,
                            float* __restrict__ gsum, int j) {
  constexpr int H  = MP ? 1 : (K / 2);
  constexpr int TW = 128 + 2 * H;          // valid tile width
  constexpr int P  = (TW + 3) & ~3;        // padded pitch (float4 aligned)
  constexpr int WN = MP ? 12 : ((8 + K - 1 + 3) & ~3);
  __shared__ __align__(16) float xs[64 * P];

  const int b  = blockIdx.y;
  const int l0 = blockIdx.x * 128;
  const int t  = threadIdx.x;
  const int tx = t & 15, ty = t >> 4;
  const int px = tx * 8;
  const float PADV = MP ? -INFINITY : 0.0f;
  const float* xb = x + (size_t)b * NIC * LL;

  float acc[8][8];
#pragma unroll
  for (int oi = 0; oi < 8; ++oi)
#pragma unroll
    for (int pi = 0; pi < 8; ++pi) acc[oi][pi] = 0.0f;

  for (int cc = 0; cc < 128; cc += 64) {
    __syncthreads();
    for (int idx = t; idx < 64 * TW; idx += 256) {
      int cil = idx / TW;
      int m   = idx - cil * TW;
      int l   = l0 - H + m;
      float v = (l >= 0 && l < LL) ? xb[(size_t)(cc + cil) * LL + l] : PADV;
      xs[cil * P + m] = v;
    }
    __syncthreads();
    for (int cil = 0; cil < 64; ++cil) {
      const int ci = cc + cil;
      float win[WN];
      const float* xrow = &xs[cil * P + px];
#pragma unroll
      for (int w4 = 0; w4 < WN / 4; ++w4)
        *(float4*)&win[w4 * 4] = *(const float4*)&xrow[w4 * 4];
      if constexpr (MP) {
        float pool[8];
#pragma unroll
        for (int pi = 0; pi < 8; ++pi)
          pool[pi] = fmaxf(fmaxf(win[pi], win[pi + 1]), win[pi + 2]);
        const float* wp = wt + ci * 128 + ty * 8;
        float4 w0 = *(const float4*)wp;
        float4 w1 = *(const float4*)(wp + 4);
        float wv[8] = {w0.x, w0.y, w0.z, w0.w, w1.x, w1.y, w1.z, w1.w};
#pragma unroll
        for (int oi = 0; oi < 8; ++oi)
#pragma unroll
          for (int pi = 0; pi < 8; ++pi)
            acc[oi][pi] = fmaf(wv[oi], pool[pi], acc[oi][pi]);
      } else {
#pragma unroll
        for (int k = 0; k < K; ++k) {
          const float* wp = wt + (ci * K + k) * 128 + ty * 8;
          float4 w0 = *(const float4*)wp;
          float4 w1 = *(const float4*)(wp + 4);
          float wv[8] = {w0.x, w0.y, w0.z, w0.w, w1.x, w1.y, w1.z, w1.w};
#pragma unroll
          for (int oi = 0; oi < 8; ++oi)
#pragma unroll
            for (int pi = 0; pi < 8; ++pi)
              acc[oi][pi] = fmaf(wv[oi], win[k + pi], acc[oi][pi]);
        }
      }
    }
  }

  unsigned short* Fb =
      Fout + (((size_t)j * BATCH + b) * NFC + ty * 8) * LL + l0 + px;
#pragma unroll
  for (int oi = 0; oi < 8; ++oi) {
    unsigned short tmp[8];
#pragma unroll
    for (int pi = 0; pi < 8; ++pi) tmp[pi] = f2bf(acc[oi][pi]);
    *(float4*)(Fb + (size_t)oi * LL) = *(float4*)tmp;
    float s = 0.0f;
#pragma unroll
    for (int pi = 0; pi < 8; ++pi) s += acc[oi][pi];
    s += __shfl_xor(s, 1);
    s += __shfl_xor(s, 2);
    s += __shfl_xor(s, 4);
    s += __shfl_xor(s, 8);
    if (tx == 0)
      atomicAdd(&gsum[((size_t)j * BATCH + b) * NFC + ty * 8 + oi], s);
  }
}

// ---------------------------------------------------------------------------
// Attention + SE head: one block per batch. gaps -> qkv -> att[5,5] -> y ->
// SE MLP -> per-channel sigmoid scale s[640]. All tiny dots in LDS.
// ---------------------------------------------------------------------------
__launch_bounds__(128)
__global__ void attn_se(const float* __restrict__ gsum,
                        const float* __restrict__ qkvw,
                        const float* __restrict__ qkvb,
                        const float* __restrict__ sew1,
                        const float* __restrict__ sew2,
                        float* __restrict__ attg, float* __restrict__ sg) {
  __shared__ float gap[640];
  __shared__ float qkvv[1920];
  __shared__ float en[100];  // [h][i][i2]
  __shared__ float att[25];
  __shared__ float h1[40];
  __shared__ float yv[640];
  const int b = blockIdx.x;
  const int t = threadIdx.x;

  for (int i = t; i < 640; i += 128) {
    int jj = i >> 7, c = i & 127;
    gap[i] = gsum[((size_t)jj * BATCH + b) * NFC + c] * (1.0f / 4096.0f);
  }
  __syncthreads();
  for (int rr = t; rr < 1920; rr += 128) {
    int i = rr / 384, r = rr - i * 384;
    const float* wr = qkvw + (size_t)r * 128;
    float a = qkvb[r];
    for (int c = 0; c < 128; ++c) a = fmaf(wr[c], gap[i * 128 + c], a);
    qkvv[i * 384 + r] = a;
  }
  __syncthreads();
  if (t < 100) {
    int h = t / 25, rem = t - h * 25, i = rem / 5, i2 = rem - i * 5;
    float e = 0.f;
    for (int d = 0; d < 32; ++d)
      e = fmaf(qkvv[i * 384 + h * 96 + d * 3],
               qkvv[i2 * 384 + h * 96 + d * 3 + 1], e);
    en[t] = e * 0.08838834764831845f;  // 1/sqrt(128)
  }
  __syncthreads();
  if (t < 20) {  // softmax over last index (i2), rows (h,i)
    float* row = &en[t * 5];
    float mx = row[0];
    for (int k = 1; k < 5; ++k) mx = fmaxf(mx, row[k]);
    float ex[5];
    float sm = 0.f;
    for (int k = 0; k < 5; ++k) { ex[k] = expf(row[k] - mx); sm += ex[k]; }
    float inv = 1.0f / sm;
    for (int k = 0; k < 5; ++k) row[k] = ex[k] * inv;
  }
  __syncthreads();
  if (t < 25) {
    float a = 0.25f * (en[t] + en[25 + t] + en[50 + t] + en[75 + t]);
    att[t] = a;
    attg[b * 25 + t] = a;
  }
  __syncthreads();
  for (int i = t; i < 640; i += 128) {  // y = att @ gaps
    int ii = i >> 7, c = i & 127;
    float a = 0.f;
    for (int jj = 0; jj < 5; ++jj)
      a = fmaf(att[ii * 5 + jj], gap[jj * 128 + c], a);
    yv[i] = a;
  }
  __syncthreads();
  if (t < 40) {
    const float* wr = sew1 + (size_t)t * 640;
    float a = 0.f;
    for (int c = 0; c < 640; ++c) a = fmaf(wr[c], yv[c], a);
    h1[t] = fmaxf(a, 0.f);
  }
  __syncthreads();
  for (int i = t; i < 640; i += 128) {
    const float* wr = sew2 + (size_t)i * 40;
    float a = 0.f;
    for (int r = 0; r < 40; ++r) a = fmaf(wr[r], h1[r], a);
    sg[(size_t)b * 640 + i] = 1.0f / (1.0f + expf(-a));
  }
}

// ---------------------------------------------------------------------------
// Weff[b][o][j*128+c] = sum_i att[b,i,j] * s[b,i*128+c] * w_bott[o,i*128+c]
// ---------------------------------------------------------------------------
__launch_bounds__(256)
__global__ void make_weff(const float* __restrict__ wbott,
                          const float* __restrict__ attg,
                          const float* __restrict__ sg,
                          float* __restrict__ weff) {
  __shared__ float att[25];
  __shared__ float s[640];
  const int b = blockIdx.y;
  const int t = threadIdx.x;
  if (t < 25) att[t] = attg[b * 25 + t];
  for (int i = t; i < 640; i += 256) s[i] = sg[(size_t)b * 640 + i];
  __syncthreads();
  const int f  = blockIdx.x * 256 + t;  // < 409600
  const int o  = f / 640;
  const int jc = f - o * 640;
  const int jj = jc >> 7, c = jc & 127;
  float a = 0.f;
#pragma unroll
  for (int i = 0; i < 5; ++i)
    a = fmaf(att[i * 5 + jj] * s[i * 128 + c],
             wbott[(size_t)o * 640 + i * 128 + c], a);
  weff[(size_t)b * 409600 + f] = a;
}

// ---------------------------------------------------------------------------
// Bottleneck GEMM: out_pre[b][o][l] = sum_{c640} Weff[b][o][c640]*Fcat[b][c640][l]
// Block tile 128o x 128l, K-tile 32, thread tile 8x8. Writes pre-BN to d_out.
// ---------------------------------------------------------------------------
__launch_bounds__(256)
__global__ void gemm_bott(const float* __restrict__ weff,
                          const unsigned short* __restrict__ F,
                          float* __restrict__ out) {
  __shared__ __align__(16) float As[32 * 132];  // [k][o], pitch 132
  __shared__ __align__(16) float Bs[32 * 132];  // [k][l], pitch 132
  const int b  = blockIdx.z;
  const int o0 = blockIdx.y * 128;
  const int l0 = blockIdx.x * 128;
  const int t  = threadIdx.x;
  const int tx = t & 15, ty = t >> 4;
  const float* wb = weff + (size_t)b * 409600;

  float acc[8][8];
#pragma unroll
  for (int oi = 0; oi < 8; ++oi)
#pragma unroll
    for (int pi = 0; pi < 8; ++pi) acc[oi][pi] = 0.0f;

  for (int k0 = 0; k0 < 640; k0 += 32) {
    __syncthreads();
#pragma unroll
    for (int i = 0; i < 4; ++i) {  // A tile: 128 rows x 32 cols
      int idx = t + i * 256;
      int row = idx >> 3;
      int col = (idx & 7) * 4;
      float4 v = *(const float4*)(wb + (size_t)(o0 + row) * 640 + k0 + col);
      As[(col + 0) * 132 + row] = v.x;
      As[(col + 1) * 132 + row] = v.y;
      As[(col + 2) * 132 + row] = v.z;
      As[(col + 3) * 132 + row] = v.w;
    }
    const int jj = k0 >> 7;
    const unsigned short* Fb =
        F + (((size_t)jj * BATCH + b) * NFC + (k0 & 127)) * LL + l0;
#pragma unroll
    for (int i = 0; i < 2; ++i) {  // B tile: 32 rows x 128 cols (bf16 -> f32)
      int idx = t + i * 256;       // < 512
      int row = idx >> 4;
      int c8  = (idx & 15) * 8;
      float4 raw = *(const float4*)(Fb + (size_t)row * LL + c8);
      const unsigned short* u = (const unsigned short*)&raw;
      float4 lo = make_float4(bf2f(u[0]), bf2f(u[1]), bf2f(u[2]), bf2f(u[3]));
      float4 hi = make_float4(bf2f(u[4]), bf2f(u[5]), bf2f(u[6]), bf2f(u[7]));
      *(float4*)&Bs[row * 132 + c8]     = lo;
      *(float4*)&Bs[row * 132 + c8 + 4] = hi;
    }
    __syncthreads();
#pragma unroll 8
    for (int k = 0; k < 32; ++k) {
      float a8[8], b8[8];
      *(float4*)&a8[0] = *(const float4*)&As[k * 132 + ty * 8];
      *(float4*)&a8[4] = *(const float4*)&As[k * 132 + ty * 8 + 4];
      *(float4*)&b8[0] = *(const float4*)&Bs[k * 132 + tx * 8];
      *(float4*)&b8[4] = *(const float4*)&Bs[k * 132 + tx * 8 + 4];
#pragma unroll
      for (int oi = 0; oi < 8; ++oi)
#pragma unroll
        for (int pi = 0; pi < 8; ++pi)
          acc[oi][pi] = fmaf(a8[oi], b8[pi], acc[oi][pi]);
    }
  }
  float* ob = out + ((size_t)b * 640 + o0 + ty * 8) * LL + l0 + tx * 8;
#pragma unroll
  for (int oi = 0; oi < 8; ++oi) {
    *(float4*)(ob + (size_t)oi * LL) =
        make_float4(acc[oi][0], acc[oi][1], acc[oi][2], acc[oi][3]);
    *(float4*)(ob + (size_t)oi * LL + 4) =
        make_float4(acc[oi][4], acc[oi][5], acc[oi][6], acc[oi][7]);
  }
}

// ---------------------------------------------------------------------------
// BN stats: one block per channel o; sums over (b,l), writes a[o], bshift[o].
// ---------------------------------------------------------------------------
__launch_bounds__(256)
__global__ void bn_stats(const float* __restrict__ out,
                         const float* __restrict__ gamma,
                         const float* __restrict__ beta,
                         float* __restrict__ ab) {
  const int o = blockIdx.x;
  const int t = threadIdx.x;
  float s = 0.f, s2 = 0.f;
  for (int i = t; i < 32 * 1024; i += 256) {
    int bb = i >> 10;
    int l4 = (i & 1023) * 4;
    float4 v = *(const float4*)(out + ((size_t)bb * 640 + o) * LL + l4);
    s  += v.x + v.y + v.z + v.w;
    s2 += v.x * v.x + v.y * v.y + v.z * v.z + v.w * v.w;
  }
#pragma unroll
  for (int m = 1; m < 64; m <<= 1) {
    s  += __shfl_xor(s, m);
    s2 += __shfl_xor(s2, m);
  }
  __shared__ float red[8];
  int lane = t & 63, w = t >> 6;
  if (lane == 0) { red[w] = s; red[4 + w] = s2; }
  __syncthreads();
  if (t == 0) {
    float S  = red[0] + red[1] + red[2] + red[3];
    float S2 = red[4] + red[5] + red[6] + red[7];
    float mean = S * (1.0f / 131072.0f);
    float var  = S2 * (1.0f / 131072.0f) - mean * mean;
    float a = gamma[o] * rsqrtf(var + 1e-5f);
    ab[o]       = a;
    ab[640 + o] = beta[o] - mean * a;
  }
}

__launch_bounds__(256)
__global__ void bn_apply(float* __restrict__ out, const float* __restrict__ ab) {
  size_t i4 = (size_t)blockIdx.x * 256 + threadIdx.x;
  if (i4 >= 20971520ull) return;
  int o = (int)((i4 >> 10) % 640);
  float a = ab[o], bs = ab[640 + o];
  float4 v = ((const float4*)out)[i4];
  v.x = fmaxf(fmaf(v.x, a, bs), 0.f);
  v.y = fmaxf(fmaf(v.y, a, bs), 0.f);
  v.z = fmaxf(fmaf(v.z, a, bs), 0.f);
  v.w = fmaxf(fmaf(v.w, a, bs), 0.f);
  ((float4*)out)[i4] = v;
}

// ---------------------------------------------------------------------------
extern "C" void kernel_launch(void* const* d_in, const int* in_sizes, int n_in,
                              void* d_out, int out_size, void* d_ws,
                              size_t ws_size, hipStream_t stream) {
  (void)in_sizes; (void)n_in; (void)out_size; (void)ws_size;
  const float* x     = (const float*)d_in[0];
  const float* w0    = (const float*)d_in[1];
  const float* w1    = (const float*)d_in[2];
  const float* w2    = (const float*)d_in[3];
  const float* w3    = (const float*)d_in[4];
  const float* wmp   = (const float*)d_in[5];
  const float* qkvw  = (const float*)d_in[6];
  const float* qkvb  = (const float*)d_in[7];
  const float* sew1  = (const float*)d_in[8];
  const float* sew2  = (const float*)d_in[9];
  const float* wbott = (const float*)d_in[10];
  const float* gamma = (const float*)d_in[11];
  const float* beta  = (const float*)d_in[12];
  float* out = (float*)d_out;

  // Workspace layout (bytes):
  //   F (bf16)  : 5*32*128*4096*2 = 167,772,160
  //   Weff (f32): 32*640*640*4    =  52,428,800
  //   wt   (f32): 573,440*4       =   2,293,760
  //   gsum (f32): 20,480*4
  //   attg (f32): 800*4 ; sg: 20,480*4 ; ab: 1,280*4
  char* ws = (char*)d_ws;
  unsigned short* F = (unsigned short*)ws;
  float* Weff = (float*)(ws + 167772160u);
  float* wt   = (float*)(ws + 167772160u + 52428800u);
  float* gsum = wt + 573440;
  float* attg = gsum + 20480;
  float* sg   = attg + 800;
  float* ab   = sg + 20480;

  hipMemsetAsync(gsum, 0, 20480 * sizeof(float), stream);

  wtrans<<<(311296 + 255) / 256, 256, 0, stream>>>(w0,  wt,          19, 311296);
  wtrans<<<(147456 + 255) / 256, 256, 0, stream>>>(w1,  wt + 311296,  9, 147456);
  wtrans<<< (81920 + 255) / 256, 256, 0, stream>>>(w2,  wt + 458752,  5,  81920);
  wtrans<<< (16384 + 255) / 256, 256, 0, stream>>>(w3,  wt + 540672,  1,  16384);
  wtrans<<< (16384 + 255) / 256, 256, 0, stream>>>(wmp, wt + 557056,  1,  16384);

  dim3 cgrid(32, 32);
  conv_branch<19, false><<<cgrid, 256, 0, stream>>>(x, wt,          F, gsum, 0);
  conv_branch<9,  false><<<cgrid, 256, 0, stream>>>(x, wt + 311296, F, gsum, 1);
  conv_branch<5,  false><<<cgrid, 256, 0, stream>>>(x, wt + 458752, F, gsum, 2);
  conv_branch<1,  false><<<cgrid, 256, 0, stream>>>(x, wt + 540672, F, gsum, 3);
  conv_branch<1,  true ><<<cgrid, 256, 0, stream>>>(x, wt + 557056, F, gsum, 4);

  attn_se<<<32, 128, 0, stream>>>(gsum, qkvw, qkvb, sew1, sew2, attg, sg);
  make_weff<<<dim3(1600, 32), 256, 0, stream>>>(wbott, attg, sg, Weff);
  gemm_bott<<<dim3(32, 5, 32), 256, 0, stream>>>(Weff, F, out);
  bn_stats<<<640, 256, 0, stream>>>(out, gamma, beta, ab);
  bn_apply<<<81920, 256, 0, stream>>>(out, ab);
}

// Round 2
// 2790.523 us; speedup vs baseline: 1.2921x; 1.2921x over previous
//
#include <hip/hip_runtime.h>
#include <math.h>

// Problem constants
#define LL 4096
#define BATCH 32
#define NIC 128
#define NFC 128

typedef __attribute__((ext_vector_type(8))) short short8;
typedef __attribute__((ext_vector_type(4))) float floatx4;

__device__ __forceinline__ unsigned short f2bf(float f) {
  unsigned u = __builtin_bit_cast(unsigned, f);
  u += 0x7fffu + ((u >> 16) & 1u);  // round-to-nearest-even
  return (unsigned short)(u >> 16);
}
__device__ __forceinline__ float bf2f(unsigned short h) {
  unsigned u = ((unsigned)h) << 16;
  return __builtin_bit_cast(float, u);
}

// ---------------------------------------------------------------------------
// Weight transpose: src [O=128][I=128][K] -> dst [(ci*K + k)*128 + o]
// ---------------------------------------------------------------------------
__global__ void wtrans(const float* __restrict__ src, float* __restrict__ dst,
                       int K, int n) {
  int f = blockIdx.x * 256 + threadIdx.x;
  if (f >= n) return;
  int o   = f / (128 * K);
  int rem = f - o * 128 * K;
  int ci  = rem / K;
  int k   = rem - ci * K;
  dst[(ci * K + k) * 128 + o] = src[f];
}

// ---------------------------------------------------------------------------
// Conv branch (fp32 VALU, unchanged math). Output now written TRANSPOSED:
// Ft[b][l][j*128 + o] (bf16) so the bottleneck MFMA GEMM gets contiguous
// k-fragments. Also accumulates GAP sums.
// ---------------------------------------------------------------------------
template <int K, bool MP>
__launch_bounds__(256)
__global__ void conv_branch(const float* __restrict__ x,
                            const float* __restrict__ wt,
                            unsigned short* __restrict__ Ft,
                            float* __restrict__ gsum, int j) {
  constexpr int H  = MP ? 1 : (K / 2);
  constexpr int TW = 128 + 2 * H;          // valid tile width
  constexpr int P  = (TW + 3) & ~3;        // padded pitch
  constexpr int WN = MP ? 12 : ((8 + K - 1 + 3) & ~3);
  __shared__ __align__(16) float xs[64 * P];

  const int b  = blockIdx.y;
  const int l0 = blockIdx.x * 128;
  const int t  = threadIdx.x;
  const int tx = t & 15, ty = t >> 4;
  const int px = tx * 8;
  const float PADV = MP ? -INFINITY : 0.0f;
  const float* xb = x + (size_t)b * NIC * LL;

  float acc[8][8];
#pragma unroll
  for (int oi = 0; oi < 8; ++oi)
#pragma unroll
    for (int pi = 0; pi < 8; ++pi) acc[oi][pi] = 0.0f;

  for (int cc = 0; cc < 128; cc += 64) {
    __syncthreads();
    for (int idx = t; idx < 64 * TW; idx += 256) {
      int cil = idx / TW;
      int m   = idx - cil * TW;
      int l   = l0 - H + m;
      float v = (l >= 0 && l < LL) ? xb[(size_t)(cc + cil) * LL + l] : PADV;
      xs[cil * P + m] = v;
    }
    __syncthreads();
    for (int cil = 0; cil < 64; ++cil) {
      const int ci = cc + cil;
      float win[WN];
      const float* xrow = &xs[cil * P + px];
#pragma unroll
      for (int w4 = 0; w4 < WN / 4; ++w4)
        *(float4*)&win[w4 * 4] = *(const float4*)&xrow[w4 * 4];
      if constexpr (MP) {
        float pool[8];
#pragma unroll
        for (int pi = 0; pi < 8; ++pi)
          pool[pi] = fmaxf(fmaxf(win[pi], win[pi + 1]), win[pi + 2]);
        const float* wp = wt + ci * 128 + ty * 8;
        float4 w0 = *(const float4*)wp;
        float4 w1 = *(const float4*)(wp + 4);
        float wv[8] = {w0.x, w0.y, w0.z, w0.w, w1.x, w1.y, w1.z, w1.w};
#pragma unroll
        for (int oi = 0; oi < 8; ++oi)
#pragma unroll
          for (int pi = 0; pi < 8; ++pi)
            acc[oi][pi] = fmaf(wv[oi], pool[pi], acc[oi][pi]);
      } else {
#pragma unroll
        for (int k = 0; k < K; ++k) {
          const float* wp = wt + (ci * K + k) * 128 + ty * 8;
          float4 w0 = *(const float4*)wp;
          float4 w1 = *(const float4*)(wp + 4);
          float wv[8] = {w0.x, w0.y, w0.z, w0.w, w1.x, w1.y, w1.z, w1.w};
#pragma unroll
          for (int oi = 0; oi < 8; ++oi)
#pragma unroll
            for (int pi = 0; pi < 8; ++pi)
              acc[oi][pi] = fmaf(wv[oi], win[k + pi], acc[oi][pi]);
        }
      }
    }
  }

  // Write transposed: Ft[b][l0+px+pi][j*128 + ty*8 + oi]
  unsigned short* Fb =
      Ft + ((size_t)b * LL + l0 + px) * 640 + j * NFC + ty * 8;
#pragma unroll
  for (int pi = 0; pi < 8; ++pi) {
    short8 v;
#pragma unroll
    for (int oi = 0; oi < 8; ++oi) v[oi] = (short)f2bf(acc[oi][pi]);
    *(short8*)&Fb[(size_t)pi * 640] = v;
  }
#pragma unroll
  for (int oi = 0; oi < 8; ++oi) {
    float s = 0.0f;
#pragma unroll
    for (int pi = 0; pi < 8; ++pi) s += acc[oi][pi];
    s += __shfl_xor(s, 1);
    s += __shfl_xor(s, 2);
    s += __shfl_xor(s, 4);
    s += __shfl_xor(s, 8);
    if (tx == 0)
      atomicAdd(&gsum[((size_t)j * BATCH + b) * NFC + ty * 8 + oi], s);
  }
}

// ---------------------------------------------------------------------------
// Attention + SE head (unchanged)
// ---------------------------------------------------------------------------
__launch_bounds__(128)
__global__ void attn_se(const float* __restrict__ gsum,
                        const float* __restrict__ qkvw,
                        const float* __restrict__ qkvb,
                        const float* __restrict__ sew1,
                        const float* __restrict__ sew2,
                        float* __restrict__ attg, float* __restrict__ sg) {
  __shared__ float gap[640];
  __shared__ float qkvv[1920];
  __shared__ float en[100];
  __shared__ float att[25];
  __shared__ float h1[40];
  __shared__ float yv[640];
  const int b = blockIdx.x;
  const int t = threadIdx.x;

  for (int i = t; i < 640; i += 128) {
    int jj = i >> 7, c = i & 127;
    gap[i] = gsum[((size_t)jj * BATCH + b) * NFC + c] * (1.0f / 4096.0f);
  }
  __syncthreads();
  for (int rr = t; rr < 1920; rr += 128) {
    int i = rr / 384, r = rr - i * 384;
    const float* wr = qkvw + (size_t)r * 128;
    float a = qkvb[r];
    for (int c = 0; c < 128; ++c) a = fmaf(wr[c], gap[i * 128 + c], a);
    qkvv[i * 384 + r] = a;
  }
  __syncthreads();
  if (t < 100) {
    int h = t / 25, rem = t - h * 25, i = rem / 5, i2 = rem - i * 5;
    float e = 0.f;
    for (int d = 0; d < 32; ++d)
      e = fmaf(qkvv[i * 384 + h * 96 + d * 3],
               qkvv[i2 * 384 + h * 96 + d * 3 + 1], e);
    en[t] = e * 0.08838834764831845f;
  }
  __syncthreads();
  if (t < 20) {
    float* row = &en[t * 5];
    float mx = row[0];
    for (int k = 1; k < 5; ++k) mx = fmaxf(mx, row[k]);
    float ex[5];
    float sm = 0.f;
    for (int k = 0; k < 5; ++k) { ex[k] = expf(row[k] - mx); sm += ex[k]; }
    float inv = 1.0f / sm;
    for (int k = 0; k < 5; ++k) row[k] = ex[k] * inv;
  }
  __syncthreads();
  if (t < 25) {
    float a = 0.25f * (en[t] + en[25 + t] + en[50 + t] + en[75 + t]);
    att[t] = a;
    attg[b * 25 + t] = a;
  }
  __syncthreads();
  for (int i = t; i < 640; i += 128) {
    int ii = i >> 7, c = i & 127;
    float a = 0.f;
    for (int jj = 0; jj < 5; ++jj)
      a = fmaf(att[ii * 5 + jj], gap[jj * 128 + c], a);
    yv[i] = a;
  }
  __syncthreads();
  if (t < 40) {
    const float* wr = sew1 + (size_t)t * 640;
    float a = 0.f;
    for (int c = 0; c < 640; ++c) a = fmaf(wr[c], yv[c], a);
    h1[t] = fmaxf(a, 0.f);
  }
  __syncthreads();
  for (int i = t; i < 640; i += 128) {
    const float* wr = sew2 + (size_t)i * 40;
    float a = 0.f;
    for (int r = 0; r < 40; ++r) a = fmaf(wr[r], h1[r], a);
    sg[(size_t)b * 640 + i] = 1.0f / (1.0f + expf(-a));
  }
}

// ---------------------------------------------------------------------------
// Weff[b][o][j*128+c] = sum_i att[b,i,j]*s[b,i*128+c]*w_bott[o,i*128+c]
// Output in bf16 (MFMA A operand).
// ---------------------------------------------------------------------------
__launch_bounds__(256)
__global__ void make_weff(const float* __restrict__ wbott,
                          const float* __restrict__ attg,
                          const float* __restrict__ sg,
                          unsigned short* __restrict__ weff) {
  __shared__ float att[25];
  __shared__ float s[640];
  const int b = blockIdx.y;
  const int t = threadIdx.x;
  if (t < 25) att[t] = attg[b * 25 + t];
  for (int i = t; i < 640; i += 256) s[i] = sg[(size_t)b * 640 + i];
  __syncthreads();
  const int f  = blockIdx.x * 256 + t;  // < 409600
  const int o  = f / 640;
  const int jc = f - o * 640;
  const int jj = jc >> 7, c = jc & 127;
  float a = 0.f;
#pragma unroll
  for (int i = 0; i < 5; ++i)
    a = fmaf(att[i * 5 + jj] * s[i * 128 + c],
             wbott[(size_t)o * 640 + i * 128 + c], a);
  weff[(size_t)b * 409600 + f] = f2bf(a);
}

// ---------------------------------------------------------------------------
// Bottleneck GEMM via bf16 MFMA.
// out_pre[b][o][l] = sum_k Weff[b][o][k] * Ft[b][l][k]   (k = 0..639)
// Block: 256 thr = 4 waves (2x2 over o,l), tile 128o x 128l, K-chunk 64.
// A-fragments direct from global (L2-served); B staged in LDS.
// Fragment layouts (m89/m91-verified):
//   A[m=lane&15][k=(lane>>4)*8+j], B[k=(lane>>4)*8+j][n=lane&15],
//   D[row=(lane>>4)*4+reg][col=lane&15]
// ---------------------------------------------------------------------------
__launch_bounds__(256)
__global__ void gemm_bott_mfma(const unsigned short* __restrict__ weff,
                               const unsigned short* __restrict__ Ft,
                               float* __restrict__ out) {
  __shared__ unsigned short Bs[128 * 64];  // [l-row][k] bf16, 16 KB
  const int b  = blockIdx.z;
  const int o0 = blockIdx.x * 128;
  const int l0 = blockIdx.y * 128;
  const int t    = threadIdx.x;
  const int lane = t & 63;
  const int w    = t >> 6;
  const int wo = w & 1, wl = w >> 1;
  const int lhi = lane >> 4;   // quad
  const int llo = lane & 15;
  const unsigned short* wb = weff + (size_t)b * 409600;
  const unsigned short* fb = Ft + (size_t)b * (size_t)LL * 640;

  floatx4 acc[4][4];
#pragma unroll
  for (int oi = 0; oi < 4; ++oi)
#pragma unroll
    for (int ni = 0; ni < 4; ++ni) acc[oi][ni] = (floatx4)0.0f;

  for (int k0 = 0; k0 < 640; k0 += 64) {
    __syncthreads();
#pragma unroll
    for (int i = 0; i < 4; ++i) {
      int chunk = i * 256 + t;      // 1024 chunks of 16 B
      int r  = chunk >> 3;          // l-row 0..127
      int co = (chunk & 7) * 8;     // k offset 0..56
      *(short8*)&Bs[r * 64 + co] =
          *(const short8*)&fb[(size_t)(l0 + r) * 640 + k0 + co];
    }
    __syncthreads();
#pragma unroll
    for (int s = 0; s < 2; ++s) {
      short8 af[4], bf[4];
#pragma unroll
      for (int oi = 0; oi < 4; ++oi) {
        int o = o0 + wo * 64 + oi * 16 + llo;
        af[oi] = *(const short8*)&wb[(size_t)o * 640 + k0 + s * 32 + lhi * 8];
      }
#pragma unroll
      for (int ni = 0; ni < 4; ++ni) {
        int n = wl * 64 + ni * 16 + llo;
        bf[ni] = *(const short8*)&Bs[n * 64 + s * 32 + lhi * 8];
      }
#pragma unroll
      for (int oi = 0; oi < 4; ++oi)
#pragma unroll
        for (int ni = 0; ni < 4; ++ni)
          acc[oi][ni] = __builtin_amdgcn_mfma_f32_16x16x32_bf16(
              af[oi], bf[ni], acc[oi][ni], 0, 0, 0);
    }
  }

#pragma unroll
  for (int oi = 0; oi < 4; ++oi) {
#pragma unroll
    for (int ni = 0; ni < 4; ++ni) {
      int o = o0 + wo * 64 + oi * 16 + lhi * 4;
      int l = l0 + wl * 64 + ni * 16 + llo;
      float* op = out + ((size_t)b * 640 + o) * LL + l;
#pragma unroll
      for (int r = 0; r < 4; ++r) op[(size_t)r * LL] = acc[oi][ni][r];
    }
  }
}

// ---------------------------------------------------------------------------
// BN stats + apply (unchanged)
// ---------------------------------------------------------------------------
__launch_bounds__(256)
__global__ void bn_stats(const float* __restrict__ out,
                         const float* __restrict__ gamma,
                         const float* __restrict__ beta,
                         float* __restrict__ ab) {
  const int o = blockIdx.x;
  const int t = threadIdx.x;
  float s = 0.f, s2 = 0.f;
  for (int i = t; i < 32 * 1024; i += 256) {
    int bb = i >> 10;
    int l4 = (i & 1023) * 4;
    float4 v = *(const float4*)(out + ((size_t)bb * 640 + o) * LL + l4);
    s  += v.x + v.y + v.z + v.w;
    s2 += v.x * v.x + v.y * v.y + v.z * v.z + v.w * v.w;
  }
#pragma unroll
  for (int m = 1; m < 64; m <<= 1) {
    s  += __shfl_xor(s, m);
    s2 += __shfl_xor(s2, m);
  }
  __shared__ float red[8];
  int lane = t & 63, w = t >> 6;
  if (lane == 0) { red[w] = s; red[4 + w] = s2; }
  __syncthreads();
  if (t == 0) {
    float S  = red[0] + red[1] + red[2] + red[3];
    float S2 = red[4] + red[5] + red[6] + red[7];
    float mean = S * (1.0f / 131072.0f);
    float var  = S2 * (1.0f / 131072.0f) - mean * mean;
    float a = gamma[o] * rsqrtf(var + 1e-5f);
    ab[o]       = a;
    ab[640 + o] = beta[o] - mean * a;
  }
}

__launch_bounds__(256)
__global__ void bn_apply(float* __restrict__ out, const float* __restrict__ ab) {
  size_t i4 = (size_t)blockIdx.x * 256 + threadIdx.x;
  if (i4 >= 20971520ull) return;
  int o = (int)((i4 >> 10) % 640);
  float a = ab[o], bs = ab[640 + o];
  float4 v = ((const float4*)out)[i4];
  v.x = fmaxf(fmaf(v.x, a, bs), 0.f);
  v.y = fmaxf(fmaf(v.y, a, bs), 0.f);
  v.z = fmaxf(fmaf(v.z, a, bs), 0.f);
  v.w = fmaxf(fmaf(v.w, a, bs), 0.f);
  ((float4*)out)[i4] = v;
}

// ---------------------------------------------------------------------------
extern "C" void kernel_launch(void* const* d_in, const int* in_sizes, int n_in,
                              void* d_out, int out_size, void* d_ws,
                              size_t ws_size, hipStream_t stream) {
  (void)in_sizes; (void)n_in; (void)out_size; (void)ws_size;
  const float* x     = (const float*)d_in[0];
  const float* w0    = (const float*)d_in[1];
  const float* w1    = (const float*)d_in[2];
  const float* w2    = (const float*)d_in[3];
  const float* w3    = (const float*)d_in[4];
  const float* wmp   = (const float*)d_in[5];
  const float* qkvw  = (const float*)d_in[6];
  const float* qkvb  = (const float*)d_in[7];
  const float* sew1  = (const float*)d_in[8];
  const float* sew2  = (const float*)d_in[9];
  const float* wbott = (const float*)d_in[10];
  const float* gamma = (const float*)d_in[11];
  const float* beta  = (const float*)d_in[12];
  float* out = (float*)d_out;

  // Workspace layout (bytes):
  //   Ft (bf16, transposed) : 32*4096*640*2 = 167,772,160
  //   Weff (bf16)           : 32*640*640*2  =  26,214,400
  //   wt (f32)              : 573,440*4     =   2,293,760
  //   gsum/attg/sg/ab (f32)
  char* ws = (char*)d_ws;
  unsigned short* Ft   = (unsigned short*)ws;
  unsigned short* Weff = (unsigned short*)(ws + 167772160u);
  float* wt   = (float*)(ws + 167772160u + 26214400u);
  float* gsum = wt + 573440;
  float* attg = gsum + 20480;
  float* sg   = attg + 800;
  float* ab   = sg + 20480;

  hipMemsetAsync(gsum, 0, 20480 * sizeof(float), stream);

  wtrans<<<(311296 + 255) / 256, 256, 0, stream>>>(w0,  wt,          19, 311296);
  wtrans<<<(147456 + 255) / 256, 256, 0, stream>>>(w1,  wt + 311296,  9, 147456);
  wtrans<<< (81920 + 255) / 256, 256, 0, stream>>>(w2,  wt + 458752,  5,  81920);
  wtrans<<< (16384 + 255) / 256, 256, 0, stream>>>(w3,  wt + 540672,  1,  16384);
  wtrans<<< (16384 + 255) / 256, 256, 0, stream>>>(wmp, wt + 557056,  1,  16384);

  dim3 cgrid(32, 32);
  conv_branch<19, false><<<cgrid, 256, 0, stream>>>(x, wt,          Ft, gsum, 0);
  conv_branch<9,  false><<<cgrid, 256, 0, stream>>>(x, wt + 311296, Ft, gsum, 1);
  conv_branch<5,  false><<<cgrid, 256, 0, stream>>>(x, wt + 458752, Ft, gsum, 2);
  conv_branch<1,  false><<<cgrid, 256, 0, stream>>>(x, wt + 540672, Ft, gsum, 3);
  conv_branch<1,  true ><<<cgrid, 256, 0, stream>>>(x, wt + 557056, Ft, gsum, 4);

  attn_se<<<32, 128, 0, stream>>>(gsum, qkvw, qkvb, sew1, sew2, attg, sg);
  make_weff<<<dim3(1600, 32), 256, 0, stream>>>(wbott, attg, sg, Weff);
  gemm_bott_mfma<<<dim3(5, 32, 32), 256, 0, stream>>>(Weff, Ft, out);
  bn_stats<<<640, 256, 0, stream>>>(out, gamma, beta, ab);
  bn_apply<<<81920, 256, 0, stream>>>(out, ab);
}

// Round 3
// 1314.319 us; speedup vs baseline: 2.7433x; 2.1232x over previous
//
#include <hip/hip_runtime.h>
#include <math.h>

// Problem constants
#define LL 4096
#define BATCH 32
#define NIC 128
#define NFC 128

typedef __attribute__((ext_vector_type(8))) short short8;
typedef __attribute__((ext_vector_type(4))) float floatx4;

__device__ __forceinline__ unsigned short f2bf(float f) {
  unsigned u = __builtin_bit_cast(unsigned, f);
  u += 0x7fffu + ((u >> 16) & 1u);  // round-to-nearest-even
  return (unsigned short)(u >> 16);
}
__device__ __forceinline__ float bf2f(unsigned short h) {
  unsigned u = ((unsigned)h) << 16;
  return __builtin_bit_cast(float, u);
}

// ---------------------------------------------------------------------------
// Weight prep: src fp32 [O=128][I=128][K] -> dst bf16 [k][o][ci]
// (MFMA A operand: lane reads 8 contiguous ci for fixed o)
// ---------------------------------------------------------------------------
__global__ void wtransb(const float* __restrict__ src,
                        unsigned short* __restrict__ dst, int K, int n) {
  int f = blockIdx.x * 256 + threadIdx.x;
  if (f >= n) return;
  int o   = f / (128 * K);
  int rem = f - o * 128 * K;
  int ci  = rem / K;
  int k   = rem - ci * K;
  dst[(k * 128 + o) * 128 + ci] = f2bf(src[f]);
}

// ---------------------------------------------------------------------------
// Prepass: x fp32 [b][ci][l] -> Xt bf16 [b][l][ci]  (LDS tile transpose)
// ---------------------------------------------------------------------------
__launch_bounds__(256)
__global__ void prep_xt(const float* __restrict__ x,
                        unsigned short* __restrict__ xt) {
  __shared__ unsigned short tb[64 * 136];
  const int b  = blockIdx.y;
  const int l0 = blockIdx.x * 64;
  const int t  = threadIdx.x;
  for (int idx = t; idx < 2048; idx += 256) {
    int ci = idx >> 4;
    int l4 = (idx & 15) * 4;
    float4 v = *(const float4*)&x[((size_t)b * 128 + ci) * LL + l0 + l4];
    tb[(l4 + 0) * 136 + ci] = f2bf(v.x);
    tb[(l4 + 1) * 136 + ci] = f2bf(v.y);
    tb[(l4 + 2) * 136 + ci] = f2bf(v.z);
    tb[(l4 + 3) * 136 + ci] = f2bf(v.w);
  }
  __syncthreads();
  for (int idx = t; idx < 1024; idx += 256) {
    int l  = idx >> 4;
    int cg = (idx & 15) * 8;
    *(short8*)&xt[((size_t)b * LL + l0 + l) * 128 + cg] =
        *(const short8*)&tb[l * 136 + cg];
  }
}

// ---------------------------------------------------------------------------
// Conv branch via bf16 MFMA.
// out[o][l] = sum_{tap,ci} w[tap][o][ci] * xsrc[ci][l + tap - H]
// Block 128o x 128l, 4 waves 2x2 (64x64 each). x tile (with halo) in LDS,
// weights from global (L2-served). MP: maxpool3 applied during staging.
// Epilogue: Ft[b][l][j*128+o] bf16 + GAP sums (shfl + atomics).
// Fragment layouts (m89/m91): A[m=lane&15][k=quad*8+j],
//   B[k=quad*8+j][n=lane&15], D[row=quad*4+r][col=lane&15]
// ---------------------------------------------------------------------------
template <int K, bool MP>
__launch_bounds__(256)
__global__ void conv_mfma(const unsigned short* __restrict__ xt,
                          const unsigned short* __restrict__ wtb,
                          unsigned short* __restrict__ Ft,
                          float* __restrict__ gsum, int j) {
  constexpr int H    = MP ? 0 : (K / 2);
  constexpr int ROWS = 128 + 2 * H;
  __shared__ unsigned short Bs[ROWS * 136];
  const int b  = blockIdx.y;
  const int l0 = blockIdx.x * 128;
  const int t  = threadIdx.x;
  const int lane = t & 63;
  const int w    = t >> 6;
  const int wo = w & 1, wl = w >> 1;
  const int lhi = lane >> 4;
  const int llo = lane & 15;
  const unsigned short* xb = xt + (size_t)b * LL * 128;

  // ---- stage x tile (bf16), halo zero-padded; MP pools 3 rows ----
  for (int idx = t; idx < ROWS * 16; idx += 256) {
    int r  = idx >> 4;
    int cg = (idx & 15) * 8;
    if constexpr (MP) {
      int l = l0 + r;
      float m[8];
#pragma unroll
      for (int e = 0; e < 8; ++e) m[e] = -INFINITY;
#pragma unroll
      for (int d = -1; d <= 1; ++d) {
        int ls = l + d;
        if (ls >= 0 && ls < LL) {
          short8 v = *(const short8*)&xb[(size_t)ls * 128 + cg];
#pragma unroll
          for (int e = 0; e < 8; ++e)
            m[e] = fmaxf(m[e], bf2f((unsigned short)v[e]));
        }
      }
      short8 o;
#pragma unroll
      for (int e = 0; e < 8; ++e) o[e] = (short)f2bf(m[e]);
      *(short8*)&Bs[r * 136 + cg] = o;
    } else {
      int l = l0 - H + r;
      short8 v = {0, 0, 0, 0, 0, 0, 0, 0};
      if (l >= 0 && l < LL) v = *(const short8*)&xb[(size_t)l * 128 + cg];
      *(short8*)&Bs[r * 136 + cg] = v;
    }
  }
  __syncthreads();

  floatx4 acc[4][4];
#pragma unroll
  for (int oi = 0; oi < 4; ++oi)
#pragma unroll
    for (int ni = 0; ni < 4; ++ni) acc[oi][ni] = (floatx4)0.0f;

  for (int tap = 0; tap < K; ++tap) {
    const unsigned short* wb = wtb + tap * 16384;
#pragma unroll
    for (int kc = 0; kc < 4; ++kc) {
      short8 af[4], bfr[4];
#pragma unroll
      for (int oi = 0; oi < 4; ++oi) {
        int o = wo * 64 + oi * 16 + llo;
        af[oi] = *(const short8*)&wb[o * 128 + kc * 32 + lhi * 8];
      }
#pragma unroll
      for (int ni = 0; ni < 4; ++ni) {
        int row = wl * 64 + ni * 16 + llo + tap;
        bfr[ni] = *(const short8*)&Bs[row * 136 + kc * 32 + lhi * 8];
      }
#pragma unroll
      for (int oi = 0; oi < 4; ++oi)
#pragma unroll
        for (int ni = 0; ni < 4; ++ni)
          acc[oi][ni] = __builtin_amdgcn_mfma_f32_16x16x32_bf16(
              af[oi], bfr[ni], acc[oi][ni], 0, 0, 0);
    }
  }

  // ---- epilogue: Ft (transposed bf16) + GAP partial sums ----
#pragma unroll
  for (int oi = 0; oi < 4; ++oi) {
#pragma unroll
    for (int ni = 0; ni < 4; ++ni) {
      int ob = wo * 64 + oi * 16 + lhi * 4;
      int l  = l0 + wl * 64 + ni * 16 + llo;
      unsigned short tmp[4];
#pragma unroll
      for (int r = 0; r < 4; ++r) tmp[r] = f2bf(acc[oi][ni][r]);
      *(uint2*)&Ft[((size_t)b * LL + l) * 640 + j * NFC + ob] = *(uint2*)tmp;
    }
  }
#pragma unroll
  for (int oi = 0; oi < 4; ++oi) {
#pragma unroll
    for (int r = 0; r < 4; ++r) {
      float ps = acc[oi][0][r] + acc[oi][1][r] + acc[oi][2][r] + acc[oi][3][r];
      ps += __shfl_xor(ps, 1);
      ps += __shfl_xor(ps, 2);
      ps += __shfl_xor(ps, 4);
      ps += __shfl_xor(ps, 8);
      if (llo == 0)
        atomicAdd(&gsum[((size_t)j * BATCH + b) * NFC + wo * 64 + oi * 16 +
                        lhi * 4 + r],
                  ps);
    }
  }
}

// ---------------------------------------------------------------------------
// Attention + SE head (unchanged)
// ---------------------------------------------------------------------------
__launch_bounds__(128)
__global__ void attn_se(const float* __restrict__ gsum,
                        const float* __restrict__ qkvw,
                        const float* __restrict__ qkvb,
                        const float* __restrict__ sew1,
                        const float* __restrict__ sew2,
                        float* __restrict__ attg, float* __restrict__ sg) {
  __shared__ float gap[640];
  __shared__ float qkvv[1920];
  __shared__ float en[100];
  __shared__ float att[25];
  __shared__ float h1[40];
  __shared__ float yv[640];
  const int b = blockIdx.x;
  const int t = threadIdx.x;

  for (int i = t; i < 640; i += 128) {
    int jj = i >> 7, c = i & 127;
    gap[i] = gsum[((size_t)jj * BATCH + b) * NFC + c] * (1.0f / 4096.0f);
  }
  __syncthreads();
  for (int rr = t; rr < 1920; rr += 128) {
    int i = rr / 384, r = rr - i * 384;
    const float* wr = qkvw + (size_t)r * 128;
    float a = qkvb[r];
    for (int c = 0; c < 128; ++c) a = fmaf(wr[c], gap[i * 128 + c], a);
    qkvv[i * 384 + r] = a;
  }
  __syncthreads();
  if (t < 100) {
    int h = t / 25, rem = t - h * 25, i = rem / 5, i2 = rem - i * 5;
    float e = 0.f;
    for (int d = 0; d < 32; ++d)
      e = fmaf(qkvv[i * 384 + h * 96 + d * 3],
               qkvv[i2 * 384 + h * 96 + d * 3 + 1], e);
    en[t] = e * 0.08838834764831845f;
  }
  __syncthreads();
  if (t < 20) {
    float* row = &en[t * 5];
    float mx = row[0];
    for (int k = 1; k < 5; ++k) mx = fmaxf(mx, row[k]);
    float ex[5];
    float sm = 0.f;
    for (int k = 0; k < 5; ++k) { ex[k] = expf(row[k] - mx); sm += ex[k]; }
    float inv = 1.0f / sm;
    for (int k = 0; k < 5; ++k) row[k] = ex[k] * inv;
  }
  __syncthreads();
  if (t < 25) {
    float a = 0.25f * (en[t] + en[25 + t] + en[50 + t] + en[75 + t]);
    att[t] = a;
    attg[b * 25 + t] = a;
  }
  __syncthreads();
  for (int i = t; i < 640; i += 128) {
    int ii = i >> 7, c = i & 127;
    float a = 0.f;
    for (int jj = 0; jj < 5; ++jj)
      a = fmaf(att[ii * 5 + jj], gap[jj * 128 + c], a);
    yv[i] = a;
  }
  __syncthreads();
  if (t < 40) {
    const float* wr = sew1 + (size_t)t * 640;
    float a = 0.f;
    for (int c = 0; c < 640; ++c) a = fmaf(wr[c], yv[c], a);
    h1[t] = fmaxf(a, 0.f);
  }
  __syncthreads();
  for (int i = t; i < 640; i += 128) {
    const float* wr = sew2 + (size_t)i * 40;
    float a = 0.f;
    for (int r = 0; r < 40; ++r) a = fmaf(wr[r], h1[r], a);
    sg[(size_t)b * 640 + i] = 1.0f / (1.0f + expf(-a));
  }
}

// ---------------------------------------------------------------------------
// Weff[b][o][j*128+c] = sum_i att[b,i,j]*s[b,i*128+c]*w_bott[o,i*128+c] (bf16)
// ---------------------------------------------------------------------------
__launch_bounds__(256)
__global__ void make_weff(const float* __restrict__ wbott,
                          const float* __restrict__ attg,
                          const float* __restrict__ sg,
                          unsigned short* __restrict__ weff) {
  __shared__ float att[25];
  __shared__ float s[640];
  const int b = blockIdx.y;
  const int t = threadIdx.x;
  if (t < 25) att[t] = attg[b * 25 + t];
  for (int i = t; i < 640; i += 256) s[i] = sg[(size_t)b * 640 + i];
  __syncthreads();
  const int f  = blockIdx.x * 256 + t;
  const int o  = f / 640;
  const int jc = f - o * 640;
  const int jj = jc >> 7, c = jc & 127;
  float a = 0.f;
#pragma unroll
  for (int i = 0; i < 5; ++i)
    a = fmaf(att[i * 5 + jj] * s[i * 128 + c],
             wbott[(size_t)o * 640 + i * 128 + c], a);
  weff[(size_t)b * 409600 + f] = f2bf(a);
}

// ---------------------------------------------------------------------------
// Bottleneck GEMM via bf16 MFMA + fused BN partial sums.
// out_pre[b][o][l] = sum_k Weff[b][o][k] * Ft[b][l][k]
// ---------------------------------------------------------------------------
__launch_bounds__(256)
__global__ void gemm_bott_mfma(const unsigned short* __restrict__ weff,
                               const unsigned short* __restrict__ Ft,
                               float* __restrict__ out,
                               float* __restrict__ bnp_s,
                               float* __restrict__ bnp_s2) {
  __shared__ unsigned short Bs[128 * 64];
  __shared__ float bnl_s[128];
  __shared__ float bnl_s2[128];
  const int b  = blockIdx.z;
  const int o0 = blockIdx.x * 128;
  const int l0 = blockIdx.y * 128;
  const int t    = threadIdx.x;
  const int lane = t & 63;
  const int w    = t >> 6;
  const int wo = w & 1, wl = w >> 1;
  const int lhi = lane >> 4;
  const int llo = lane & 15;
  const unsigned short* wb = weff + (size_t)b * 409600;
  const unsigned short* fb = Ft + (size_t)b * (size_t)LL * 640;
  if (t < 128) { bnl_s[t] = 0.f; bnl_s2[t] = 0.f; }

  floatx4 acc[4][4];
#pragma unroll
  for (int oi = 0; oi < 4; ++oi)
#pragma unroll
    for (int ni = 0; ni < 4; ++ni) acc[oi][ni] = (floatx4)0.0f;

  for (int k0 = 0; k0 < 640; k0 += 64) {
    __syncthreads();
#pragma unroll
    for (int i = 0; i < 4; ++i) {
      int chunk = i * 256 + t;
      int r  = chunk >> 3;
      int co = (chunk & 7) * 8;
      *(short8*)&Bs[r * 64 + co] =
          *(const short8*)&fb[(size_t)(l0 + r) * 640 + k0 + co];
    }
    __syncthreads();
#pragma unroll
    for (int s = 0; s < 2; ++s) {
      short8 af[4], bf[4];
#pragma unroll
      for (int oi = 0; oi < 4; ++oi) {
        int o = o0 + wo * 64 + oi * 16 + llo;
        af[oi] = *(const short8*)&wb[(size_t)o * 640 + k0 + s * 32 + lhi * 8];
      }
#pragma unroll
      for (int ni = 0; ni < 4; ++ni) {
        int n = wl * 64 + ni * 16 + llo;
        bf[ni] = *(const short8*)&Bs[n * 64 + s * 32 + lhi * 8];
      }
#pragma unroll
      for (int oi = 0; oi < 4; ++oi)
#pragma unroll
        for (int ni = 0; ni < 4; ++ni)
          acc[oi][ni] = __builtin_amdgcn_mfma_f32_16x16x32_bf16(
              af[oi], bf[ni], acc[oi][ni], 0, 0, 0);
    }
  }

#pragma unroll
  for (int oi = 0; oi < 4; ++oi) {
#pragma unroll
    for (int ni = 0; ni < 4; ++ni) {
      int o = o0 + wo * 64 + oi * 16 + lhi * 4;
      int l = l0 + wl * 64 + ni * 16 + llo;
      float* op = out + ((size_t)b * 640 + o) * LL + l;
#pragma unroll
      for (int r = 0; r < 4; ++r) op[(size_t)r * LL] = acc[oi][ni][r];
    }
  }
  // BN partials: sum / sum-of-squares over this block's 128 l per o
#pragma unroll
  for (int oi = 0; oi < 4; ++oi) {
#pragma unroll
    for (int r = 0; r < 4; ++r) {
      float ps = 0.f, ps2 = 0.f;
#pragma unroll
      for (int ni = 0; ni < 4; ++ni) {
        float v = acc[oi][ni][r];
        ps += v;
        ps2 += v * v;
      }
      ps  += __shfl_xor(ps, 1);  ps  += __shfl_xor(ps, 2);
      ps  += __shfl_xor(ps, 4);  ps  += __shfl_xor(ps, 8);
      ps2 += __shfl_xor(ps2, 1); ps2 += __shfl_xor(ps2, 2);
      ps2 += __shfl_xor(ps2, 4); ps2 += __shfl_xor(ps2, 8);
      if (llo == 0) {
        int ol = wo * 64 + oi * 16 + lhi * 4 + r;
        atomicAdd(&bnl_s[ol], ps);
        atomicAdd(&bnl_s2[ol], ps2);
      }
    }
  }
  __syncthreads();
  if (t < 128) {
    size_t slot = ((size_t)(blockIdx.y * 32 + blockIdx.z) * 5 + blockIdx.x) *
                      128 + t;
    bnp_s[slot]  = bnl_s[t];
    bnp_s2[slot] = bnl_s2[t];
  }
}

// ---------------------------------------------------------------------------
// BN finalize: reduce 1024 partials per channel -> scale a, shift b
// ---------------------------------------------------------------------------
__launch_bounds__(256)
__global__ void bn_finalize(const float* __restrict__ bnp_s,
                            const float* __restrict__ bnp_s2,
                            const float* __restrict__ gamma,
                            const float* __restrict__ beta,
                            float* __restrict__ ab) {
  const int o = blockIdx.x;
  const int t = threadIdx.x;
  const int ot = o >> 7, oc = o & 127;
  float s = 0.f, s2 = 0.f;
  for (int lb = t; lb < 1024; lb += 256) {
    size_t idx = ((size_t)lb * 5 + ot) * 128 + oc;
    s  += bnp_s[idx];
    s2 += bnp_s2[idx];
  }
#pragma unroll
  for (int m = 1; m < 64; m <<= 1) {
    s  += __shfl_xor(s, m);
    s2 += __shfl_xor(s2, m);
  }
  __shared__ float red[8];
  int lane = t & 63, w = t >> 6;
  if (lane == 0) { red[w] = s; red[4 + w] = s2; }
  __syncthreads();
  if (t == 0) {
    float S  = red[0] + red[1] + red[2] + red[3];
    float S2 = red[4] + red[5] + red[6] + red[7];
    float mean = S * (1.0f / 131072.0f);
    float var  = S2 * (1.0f / 131072.0f) - mean * mean;
    float a = gamma[o] * rsqrtf(var + 1e-5f);
    ab[o]       = a;
    ab[640 + o] = beta[o] - mean * a;
  }
}

__launch_bounds__(256)
__global__ void bn_apply(float* __restrict__ out, const float* __restrict__ ab) {
  size_t i4 = (size_t)blockIdx.x * 256 + threadIdx.x;
  if (i4 >= 20971520ull) return;
  int o = (int)((i4 >> 10) % 640);
  float a = ab[o], bs = ab[640 + o];
  float4 v = ((const float4*)out)[i4];
  v.x = fmaxf(fmaf(v.x, a, bs), 0.f);
  v.y = fmaxf(fmaf(v.y, a, bs), 0.f);
  v.z = fmaxf(fmaf(v.z, a, bs), 0.f);
  v.w = fmaxf(fmaf(v.w, a, bs), 0.f);
  ((float4*)out)[i4] = v;
}

// ---------------------------------------------------------------------------
extern "C" void kernel_launch(void* const* d_in, const int* in_sizes, int n_in,
                              void* d_out, int out_size, void* d_ws,
                              size_t ws_size, hipStream_t stream) {
  (void)in_sizes; (void)n_in; (void)out_size; (void)ws_size;
  const float* x     = (const float*)d_in[0];
  const float* w0    = (const float*)d_in[1];
  const float* w1    = (const float*)d_in[2];
  const float* w2    = (const float*)d_in[3];
  const float* w3    = (const float*)d_in[4];
  const float* wmp   = (const float*)d_in[5];
  const float* qkvw  = (const float*)d_in[6];
  const float* qkvb  = (const float*)d_in[7];
  const float* sew1  = (const float*)d_in[8];
  const float* sew2  = (const float*)d_in[9];
  const float* wbott = (const float*)d_in[10];
  const float* gamma = (const float*)d_in[11];
  const float* beta  = (const float*)d_in[12];
  float* out = (float*)d_out;

  // Workspace layout (bytes):
  //   Ft (bf16 [b][l][640])        : 167,772,160
  //   union { Xt bf16 [b][l][128] (33,554,432) ; Weff bf16 (26,214,400) }
  //     (Xt consumed by convs before make_weff writes Weff)
  //   wtb bf16                     : 1,146,880
  //   f32 tail: gsum/attg/sg/ab/bnp_s/bnp_s2
  char* ws = (char*)d_ws;
  unsigned short* Ft   = (unsigned short*)ws;
  unsigned short* XtW  = (unsigned short*)(ws + 167772160u);
  unsigned short* Xt   = XtW;
  unsigned short* Weff = XtW;
  unsigned short* wtb  = (unsigned short*)(ws + 167772160u + 33554432u);
  float* f32a  = (float*)(ws + 167772160u + 33554432u + 1146880u);
  float* gsum  = f32a;              // 20480
  float* attg  = gsum + 20480;      // 800
  float* sg    = attg + 800;        // 20480
  float* ab    = sg + 20480;        // 1280
  float* bnp_s  = ab + 1280;        // 655360
  float* bnp_s2 = bnp_s + 655360;   // 655360

  hipMemsetAsync(gsum, 0, 20480 * sizeof(float), stream);

  wtransb<<<(311296 + 255) / 256, 256, 0, stream>>>(w0,  wtb,          19, 311296);
  wtransb<<<(147456 + 255) / 256, 256, 0, stream>>>(w1,  wtb + 311296,  9, 147456);
  wtransb<<< (81920 + 255) / 256, 256, 0, stream>>>(w2,  wtb + 458752,  5,  81920);
  wtransb<<< (16384 + 255) / 256, 256, 0, stream>>>(w3,  wtb + 540672,  1,  16384);
  wtransb<<< (16384 + 255) / 256, 256, 0, stream>>>(wmp, wtb + 557056,  1,  16384);

  prep_xt<<<dim3(64, 32), 256, 0, stream>>>(x, Xt);

  dim3 cgrid(32, 32);
  conv_mfma<19, false><<<cgrid, 256, 0, stream>>>(Xt, wtb,          Ft, gsum, 0);
  conv_mfma<9,  false><<<cgrid, 256, 0, stream>>>(Xt, wtb + 311296, Ft, gsum, 1);
  conv_mfma<5,  false><<<cgrid, 256, 0, stream>>>(Xt, wtb + 458752, Ft, gsum, 2);
  conv_mfma<1,  false><<<cgrid, 256, 0, stream>>>(Xt, wtb + 540672, Ft, gsum, 3);
  conv_mfma<1,  true ><<<cgrid, 256, 0, stream>>>(Xt, wtb + 557056, Ft, gsum, 4);

  attn_se<<<32, 128, 0, stream>>>(gsum, qkvw, qkvb, sew1, sew2, attg, sg);
  make_weff<<<dim3(1600, 32), 256, 0, stream>>>(wbott, attg, sg, Weff);
  gemm_bott_mfma<<<dim3(5, 32, 32), 256, 0, stream>>>(Weff, Ft, out, bnp_s,
                                                      bnp_s2);
  bn_finalize<<<640, 256, 0, stream>>>(bnp_s, bnp_s2, gamma, beta, ab);
  bn_apply<<<81920, 256, 0, stream>>>(out, ab);
}